// Round 3
// baseline (741.269 us; speedup 1.0000x reference)
//
#include <hip/hip_runtime.h>
#include <hip/hip_bf16.h>
#include <stdint.h>

// Problem constants
#define B_  32
#define T_  1024
#define N_  256
#define D_  1024
#define TD_ 768
#define H_  16
#define C_  64
#define TE_ 2048

typedef __bf16 bf16x8 __attribute__((ext_vector_type(8)));
typedef __bf16 bf16x4 __attribute__((ext_vector_type(4)));
typedef float  f32x4  __attribute__((ext_vector_type(4)));

// async global->LDS, 16B per lane; lds dest must be wave-uniform base (+lane*16)
__device__ __forceinline__ void gll16(const void* g, void* l) {
  __builtin_amdgcn_global_load_lds(
      (const __attribute__((address_space(1))) unsigned int*)g,
      (__attribute__((address_space(3))) unsigned int*)l, 16, 0, 0);
}

// ---------------------------------------------------------------------------
__global__ void fill_val(float* o, float v, int n) {
  int i = blockIdx.x * 256 + threadIdx.x;
  if (i < n) o[i] = v;
}

// concat bias: o[0:1024]=a, o[1024:2048]=b
__global__ void concat2(const float* __restrict__ a, const float* __restrict__ b,
                        float* __restrict__ o) {
  int i = blockIdx.x * 256 + threadIdx.x;
  if (i < 1024) o[i] = a[i];
  else if (i < 2048) o[i] = b[i - 1024];
}

// ---------------------------------------------------------------------------
// Tiled transpose + cast: out_bf16[C,R] = in_f32[R,C]^T
// ---------------------------------------------------------------------------
__global__ void transpose_cast(const float* __restrict__ in,
                               __bf16* __restrict__ out, int R, int C) {
  __shared__ float t[32][33];
  int c0 = blockIdx.x * 32, r0 = blockIdx.y * 32;
  int x = threadIdx.x, y4 = threadIdx.y;  // (32,8)
#pragma unroll
  for (int i = 0; i < 4; i++) {
    int rr = y4 * 4 + i;
    t[rr][x] = in[(size_t)(r0 + rr) * C + c0 + x];
  }
  __syncthreads();
#pragma unroll
  for (int i = 0; i < 4; i++) {
    int rr = y4 * 4 + i;
    out[(size_t)(c0 + rr) * R + r0 + x] = (__bf16)t[x][rr];
  }
}

// ---------------------------------------------------------------------------
// LayerNorm D=1024, float4 vectorized: thread owns cols tid*4..+3
// ---------------------------------------------------------------------------
__global__ __launch_bounds__(256)
void ln1024(const float* __restrict__ x, const float* __restrict__ g,
            const float* __restrict__ bb, __bf16* __restrict__ out) {
  size_t row = blockIdx.x;
  int c4 = threadIdx.x * 4;
  f32x4 v = *(const f32x4*)(x + row * D_ + c4);
  float s = v[0] + v[1] + v[2] + v[3];
  float s2 = v[0]*v[0] + v[1]*v[1] + v[2]*v[2] + v[3]*v[3];
#pragma unroll
  for (int off = 32; off; off >>= 1) {
    s += __shfl_down(s, off);
    s2 += __shfl_down(s2, off);
  }
  __shared__ float red[8];
  int wave = threadIdx.x >> 6, lane = threadIdx.x & 63;
  if (lane == 0) { red[wave] = s; red[4 + wave] = s2; }
  __syncthreads();
  if (threadIdx.x == 0) {
    float a = 0.f, c = 0.f;
    for (int w = 0; w < 4; w++) { a += red[w]; c += red[4 + w]; }
    red[0] = a; red[4] = c;
  }
  __syncthreads();
  float mu = red[0] / D_;
  float var = red[4] / D_ - mu * mu;
  float rstd = rsqrtf(var + 1e-5f);
  f32x4 gg = *(const f32x4*)(g + c4);
  f32x4 bbv = *(const f32x4*)(bb + c4);
  bf16x4 o;
#pragma unroll
  for (int t = 0; t < 4; t++) o[t] = (__bf16)((v[t] - mu) * rstd * gg[t] + bbv[t]);
  *(bf16x4*)(out + row * D_ + c4) = o;
}

// generic row LN (used for TD=768), scalar
__global__ __launch_bounds__(256)
void ln_rows(const float* __restrict__ x, const float* __restrict__ g,
             const float* __restrict__ bb, __bf16* __restrict__ out, int D) {
  size_t row = blockIdx.x;
  const float* xr = x + row * (size_t)D;
  int tid = threadIdx.x;
  int cnt = D >> 8;
  float v[4];
  float s = 0.f, s2 = 0.f;
  for (int i = 0; i < cnt; i++) {
    float f = xr[tid + i * 256];
    v[i] = f; s += f; s2 += f * f;
  }
#pragma unroll
  for (int off = 32; off; off >>= 1) {
    s += __shfl_down(s, off);
    s2 += __shfl_down(s2, off);
  }
  __shared__ float red[8];
  int wave = tid >> 6, lane = tid & 63;
  if (lane == 0) { red[wave] = s; red[4 + wave] = s2; }
  __syncthreads();
  if (tid == 0) {
    float a = 0.f, c = 0.f;
    for (int w = 0; w < 4; w++) { a += red[w]; c += red[4 + w]; }
    red[0] = a; red[4] = c;
  }
  __syncthreads();
  float mu = red[0] / D;
  float var = red[4] / D - mu * mu;
  float rstd = rsqrtf(var + 1e-5f);
  for (int i = 0; i < cnt; i++) {
    int c = tid + i * 256;
    out[row * (size_t)D + c] = (__bf16)((v[i] - mu) * rstd * g[c] + bb[c]);
  }
}

// ---------------------------------------------------------------------------
// GEMM: C[M,N] = A[M,K](bf16) @ BT[N,K](bf16) + bias(f32)
// 256x256x64 tile, 8 waves (2Mx4N), double-buffered 128KB LDS.
// R3: two-barrier phase windows (m201 8-phase template form):
//   mem window {stage 2 gll16 + ds_reads} -> barrier A -> lgkmcnt(0) ->
//   setprio(1) 16 MFMA setprio(0) -> vmcnt(e_p) -> barrier B
// The end-of-phase vmcnt gates the NEXT phase's ds_reads (placed before
// barrier B so the cross-wave staging guarantee holds). Own-wave ledger
// (stage spread P0:B0B1 P1:B2B3 P2:A0A1 P3:A2A3, data for tile t staged
// during t-1): steady end-waits (4,5,6,3); final tile (2,1,0,0). Coverage
// identical to R1's proven (3,4,5,6) front-waits.
//
// LDS layout per 64KB buffer: [B tile 32KB][A tile 32KB], row-major
// [256 rows][64 bf16 = 128B], 16B-chunk XOR swizzle: chunk seg' = seg^(row&7)
// applied on the GLOBAL source at stage time (gll16 dest must be linear) and
// identically on the ds_read address -> bank-conflict-free b128 frag reads.
// EPI==1: add residual res(f32). CT = output type (bf16 or float).
// ---------------------------------------------------------------------------
#define WB_(n) asm volatile("s_waitcnt vmcnt(" #n ")" ::: "memory")
#define WB(n) WB_(n)
#define BARR() asm volatile("s_barrier" ::: "memory")
#define LGKM0()                                             \
  do {                                                      \
    asm volatile("s_waitcnt lgkmcnt(0)" ::: "memory");      \
    __builtin_amdgcn_sched_barrier(0);                      \
  } while (0)

template <int EPI, typename CT>
__global__ __launch_bounds__(512, 2)
void gemm256(const __bf16* __restrict__ A, const __bf16* __restrict__ BT,
             const float* __restrict__ bias, const float* __restrict__ res,
             CT* __restrict__ C, int M, int N, int K, int NT) {
  __shared__ char smem[131072];
  const int tid = threadIdx.x;
  const int ln = tid & 63, wv = tid >> 6;

  // T1: bijective XCD swizzle (gridDim.x % 8 == 0 for all our shapes);
  // consecutive swz within an XCD share the same A panel (same m-tile).
  const int nwg = gridDim.x;
  const int swz = (blockIdx.x & 7) * (nwg >> 3) + (blockIdx.x >> 3);
  const int m0 = (swz / NT) * 256, n0 = (swz % NT) * 256;

  const int wm = (wv >> 2) * 128, wn = (wv & 3) * 64;
  const int lr = ln & 15;
  // fragment k-offsets within a 128B row, XOR-swizzled (row&7 == lr&7 for all
  // fragment rows since wm/wn/p*32/ar*16/j*16 are multiples of 8 mod 8 = 0)
  const int xorv = (lr & 7) << 4;
  const int k16 = (ln >> 4) * 16;
  const int koff0 = k16 ^ xorv;          // kk = 0
  const int koff1 = (64 + k16) ^ xorv;   // kk = 1

  // stage source pointers (global side carries the swizzle)
  const int brow = tid >> 3;                       // 0..63 within a B slot
  const int bseg = (tid & 7) ^ (brow & 7);
  const __bf16* Bg = BT + (size_t)(n0 + brow) * K + bseg * 8;
  const int ahalf = tid >> 8, au = tid & 255;
  const int arow = au >> 3;                        // 0..31 within an A slice
  const int aseg = (au & 7) ^ (arow & 7);
  const __bf16* Ag = A + (size_t)(m0 + ahalf * 128 + arow) * K + aseg * 8;

  // wave-uniform LDS stage bases (gll16 adds lane*16)
  char* sBstage = smem + wv * 1024;
  char* sAstage = smem + 32768 + ahalf * 16384 + (wv & 3) * 1024;

  const int nt = K >> 6;  // K-tiles of 64 (16 for K=1024, 12 for K=768)
  f32x4 acc[8][4] = {};
  bf16x8 bfr[4][2], af[2][2];

#define STAGE_B(bf, s, k0) \
  gll16(Bg + (size_t)(s) * 64 * K + (k0), sBstage + (bf) * 65536 + (s) * 8192)
#define STAGE_A(bf, p, k0) \
  gll16(Ag + (size_t)(p) * 32 * K + (k0), sAstage + (bf) * 65536 + (p) * 4096)
#define LDA(pp, ar, kf) \
  (*(const bf16x8*)(sArd + ((wm + (pp) * 32 + (ar) * 16 + lr) * 128) + (kf)))

#define DO_MFMA(pp)                                                          \
  do {                                                                       \
    __builtin_amdgcn_s_setprio(1);                                           \
    _Pragma("unroll") for (int ar = 0; ar < 2; ++ar) {                       \
      _Pragma("unroll") for (int j = 0; j < 4; ++j) {                        \
        acc[(pp) * 2 + ar][j] = __builtin_amdgcn_mfma_f32_16x16x32_bf16(     \
            af[ar][0], bfr[j][0], acc[(pp) * 2 + ar][j], 0, 0, 0);           \
        acc[(pp) * 2 + ar][j] = __builtin_amdgcn_mfma_f32_16x16x32_bf16(     \
            af[ar][1], bfr[j][1], acc[(pp) * 2 + ar][j], 0, 0, 0);           \
      }                                                                      \
    }                                                                        \
    __builtin_amdgcn_s_setprio(0);                                           \
    __builtin_amdgcn_sched_barrier(0);                                       \
  } while (0)

#define TILE(buf, kst, PF, e0, e1, e2, e3)                                   \
  do {                                                                       \
    const char* sBrd = smem + (buf) * 65536;                                 \
    const char* sArd = sBrd + 32768;                                         \
    /* ---- P0 mem window ---- */                                            \
    if (PF) { STAGE_B((buf) ^ 1, 0, kst); STAGE_B((buf) ^ 1, 1, kst); }      \
    _Pragma("unroll") for (int j = 0; j < 4; ++j) {                          \
      bfr[j][0] = *(const bf16x8*)(sBrd + (wn + j * 16 + lr) * 128 + koff0); \
      bfr[j][1] = *(const bf16x8*)(sBrd + (wn + j * 16 + lr) * 128 + koff1); \
    }                                                                        \
    af[0][0] = LDA(0, 0, koff0); af[0][1] = LDA(0, 0, koff1);                \
    af[1][0] = LDA(0, 1, koff0); af[1][1] = LDA(0, 1, koff1);                \
    BARR(); LGKM0();                                                         \
    DO_MFMA(0);                                                              \
    WB(e0); BARR();                                                          \
    /* ---- P1 mem window ---- */                                            \
    if (PF) { STAGE_B((buf) ^ 1, 2, kst); STAGE_B((buf) ^ 1, 3, kst); }      \
    af[0][0] = LDA(1, 0, koff0); af[0][1] = LDA(1, 0, koff1);                \
    af[1][0] = LDA(1, 1, koff0); af[1][1] = LDA(1, 1, koff1);                \
    BARR(); LGKM0();                                                         \
    DO_MFMA(1);                                                              \
    WB(e1); BARR();                                                          \
    /* ---- P2 mem window ---- */                                            \
    if (PF) { STAGE_A((buf) ^ 1, 0, kst); STAGE_A((buf) ^ 1, 1, kst); }      \
    af[0][0] = LDA(2, 0, koff0); af[0][1] = LDA(2, 0, koff1);                \
    af[1][0] = LDA(2, 1, koff0); af[1][1] = LDA(2, 1, koff1);                \
    BARR(); LGKM0();                                                         \
    DO_MFMA(2);                                                              \
    WB(e2); BARR();                                                          \
    /* ---- P3 mem window ---- */                                            \
    if (PF) { STAGE_A((buf) ^ 1, 2, kst); STAGE_A((buf) ^ 1, 3, kst); }      \
    af[0][0] = LDA(3, 0, koff0); af[0][1] = LDA(3, 0, koff1);                \
    af[1][0] = LDA(3, 1, koff0); af[1][1] = LDA(3, 1, koff1);                \
    BARR(); LGKM0();                                                         \
    DO_MFMA(3);                                                              \
    WB(e3); BARR();                                                          \
  } while (0)

  // prologue: stage tile 0 into buf 0 (B first, then A); gate P0 reads
  STAGE_B(0, 0, 0); STAGE_B(0, 1, 0); STAGE_B(0, 2, 0); STAGE_B(0, 3, 0);
  STAGE_A(0, 0, 0); STAGE_A(0, 1, 0); STAGE_A(0, 2, 0); STAGE_A(0, 3, 0);
  WB(3); BARR();

  int kst = 64;
  const int npair = (nt >> 1) - 1;
  for (int tt = 0; tt < npair; ++tt) {
    TILE(0, kst, 1, 4, 5, 6, 3); kst += 64;
    TILE(1, kst, 1, 4, 5, 6, 3); kst += 64;
  }
  TILE(0, kst, 1, 4, 5, 6, 3);   // tile nt-2 stages tile nt-1
  TILE(1, 0, 0, 2, 1, 0, 0);     // tile nt-1, no prefetch, drain

#undef TILE
#undef DO_MFMA
#undef LDA
#undef STAGE_A
#undef STAGE_B

  // ---- epilogue: per-wave-private LDS re-swizzle, coalesced 16B stores.
  // C/D layout: col = lane&15, row = (lane>>4)*4 + reg   [m89-verified]
  __syncthreads();
  float* scratch = (float*)smem + wv * 1088;  // 16 rows x 68 fp32 (16B-aligned)
  const int qd = ln >> 4;
#pragma unroll
  for (int i = 0; i < 8; ++i) {
#pragma unroll
    for (int j = 0; j < 4; ++j)
#pragma unroll
      for (int r = 0; r < 4; ++r)
        scratch[(qd * 4 + r) * 68 + j * 16 + lr] = acc[i][j][r];
    asm volatile("s_waitcnt lgkmcnt(0)" ::: "memory");
#pragma unroll
    for (int s = 0; s < 4; ++s) {
      int rr = qd + 4 * s;
      f32x4 vv = *(f32x4*)&scratch[rr * 68 + lr * 4];
      int row = m0 + wm + i * 16 + rr;
      int col = n0 + wn + lr * 4;
      size_t idx = (size_t)row * N + col;
      vv += *(const f32x4*)&bias[col];
      if (EPI == 1) vv += *(const f32x4*)&res[idx];
      if constexpr (sizeof(CT) == 4) {
        *(f32x4*)&C[idx] = vv;
      } else {
        bf16x4 o;
#pragma unroll
        for (int t2 = 0; t2 < 4; ++t2) o[t2] = (__bf16)vv[t2];
        *(bf16x4*)&C[idx] = o;
      }
    }
    asm volatile("s_waitcnt lgkmcnt(0)" ::: "memory");
  }
}

// ---------------------------------------------------------------------------
// attn[b,h,c,d] = sum_n softmax_n(k)[n,c] * v[n,d], softmax fused.
// kv: [B, N, 2048] bf16, k = cols h*64.. , v = cols 1024+h*64..
// ---------------------------------------------------------------------------
__global__ __launch_bounds__(256)
void kv_attn(const __bf16* __restrict__ kv, float* __restrict__ attn) {
  int h = blockIdx.x & 15, b = blockIdx.x >> 4;
  __shared__ __bf16 sK[256 * 72];  // [n][c], stride 72 (144B, 16B-aligned rows)
  __shared__ float sV[32 * 64];
  __shared__ float sInv[64];
  int tid = threadIdx.x;
  const __bf16* kb = kv + (size_t)b * N_ * 2048 + h * C_;
  const __bf16* vb = kb + 1024;

  // stage all of k: thread t loads row t (64 bf16)
  {
    const __bf16* src = kb + (size_t)tid * 2048;
#pragma unroll
    for (int j = 0; j < 8; j++)
      *(bf16x8*)&sK[tid * 72 + j * 8] = *(const bf16x8*)(src + j * 8);
  }
  __syncthreads();

  // per-column softmax stats: 4 threads per column c, each covers 64 n's
  {
    int c = tid >> 2, qq = tid & 3;
    float m = -1e30f;
    for (int t = 0; t < 64; t++)
      m = fmaxf(m, (float)sK[(qq * 64 + t) * 72 + c]);
    m = fmaxf(m, __shfl_xor(m, 1));
    m = fmaxf(m, __shfl_xor(m, 2));
    float s = 0.f;
    for (int t = 0; t < 64; t++) {
      int idx = (qq * 64 + t) * 72 + c;
      float e = __expf((float)sK[idx] - m);
      sK[idx] = (__bf16)e;
      s += e;
    }
    s += __shfl_xor(s, 1);
    s += __shfl_xor(s, 2);
    if (qq == 0) sInv[c] = 1.f / s;
  }
  __syncthreads();

  int c0 = (tid & 15) * 4, d0 = (tid >> 4) * 4;
  float acc[4][4] = {};
  for (int n0 = 0; n0 < N_; n0 += 32) {
    __syncthreads();
    {
      int r = tid >> 3, s8 = (tid & 7) * 8;
      bf16x8 vv8 = *(const bf16x8*)(vb + (size_t)(n0 + r) * 2048 + s8);
#pragma unroll
      for (int j = 0; j < 8; j++) sV[r * 64 + s8 + j] = (float)vv8[j];
    }
    __syncthreads();
    for (int n = 0; n < 32; n++) {
      bf16x4 kk = *(const bf16x4*)&sK[(n0 + n) * 72 + c0];
      f32x4 vd = *(const f32x4*)&sV[n * 64 + d0];
#pragma unroll
      for (int i = 0; i < 4; i++) {
        float kf = (float)kk[i];
#pragma unroll
        for (int j = 0; j < 4; j++) acc[i][j] += kf * vd[j];
      }
    }
  }
  float* ab = attn + (size_t)(b * H_ + h) * 4096;
#pragma unroll
  for (int i = 0; i < 4; i++) {
    float inv = sInv[c0 + i];
    f32x4 o;
#pragma unroll
    for (int j = 0; j < 4; j++) o[j] = acc[i][j] * inv;
    *(f32x4*)&ab[(c0 + i) * 64 + d0] = o;
  }
}

// ---------------------------------------------------------------------------
// y[b,t,h,:] = softmax_c(q[b,t,h,:]) @ attn[b,h]   (channel softmax fused)
// In-place safe (y aliases q): q tile fully staged to LDS before writes.
// ---------------------------------------------------------------------------
__global__ __launch_bounds__(256)
void qattn_y(const __bf16* __restrict__ q, const float* __restrict__ attn,
             __bf16* __restrict__ y) {
  int tt = blockIdx.x * 64;
  int h = blockIdx.y, b = blockIdx.z;
  __shared__ float sQ[64 * 65];  // [c][r], stride 65
  __shared__ float sA[64 * 64];  // [c][d]
  int tid = threadIdx.x;
  const __bf16* qb = q + ((size_t)b * T_ + tt) * D_ + h * C_;
#pragma unroll
  for (int it = 0; it < 2; it++) {
    int r = (tid >> 3) + it * 32;
    int cc = (tid & 7) * 8;
    bf16x8 vv = *(const bf16x8*)(qb + (size_t)r * D_ + cc);
#pragma unroll
    for (int j = 0; j < 8; j++) sQ[(cc + j) * 65 + r] = (float)vv[j];
  }
  const float* ab = attn + (size_t)(b * H_ + h) * 4096;
  for (int i = tid; i < 1024; i += 256) ((f32x4*)sA)[i] = ((const f32x4*)ab)[i];
  __syncthreads();
  // softmax over c per row r: 4 threads/row, each covers 16 c's
  {
    int r = tid >> 2, sub = tid & 3;
    float m = -1e30f;
#pragma unroll
    for (int j = 0; j < 16; j++)
      m = fmaxf(m, sQ[(sub * 16 + j) * 65 + r]);
    m = fmaxf(m, __shfl_xor(m, 1));
    m = fmaxf(m, __shfl_xor(m, 2));
    float s = 0.f;
#pragma unroll
    for (int j = 0; j < 16; j++) {
      int idx = (sub * 16 + j) * 65 + r;
      float e = __expf(sQ[idx] - m);
      sQ[idx] = e;
      s += e;
    }
    s += __shfl_xor(s, 1);
    s += __shfl_xor(s, 2);
    float inv = 1.f / s;
#pragma unroll
    for (int j = 0; j < 16; j++) sQ[(sub * 16 + j) * 65 + r] *= inv;
  }
  __syncthreads();
  int r0 = (tid >> 4) * 4, d0 = (tid & 15) * 4;
  float acc[4][4] = {};
  for (int c = 0; c < 64; c++) {
    f32x4 qv = *(const f32x4*)&sQ[c * 65 + r0];
    f32x4 av = *(const f32x4*)&sA[c * 64 + d0];
#pragma unroll
    for (int i = 0; i < 4; i++)
#pragma unroll
      for (int j = 0; j < 4; j++) acc[i][j] += qv[i] * av[j];
  }
  __bf16* yb = y + ((size_t)b * T_ + tt) * D_ + h * C_;
#pragma unroll
  for (int i = 0; i < 4; i++) {
    bf16x4 o;
#pragma unroll
    for (int j = 0; j < 4; j++) o[j] = (__bf16)acc[i][j];
    *(bf16x4*)(yb + (size_t)(r0 + i) * D_ + d0) = o;
  }
}

// ---------------------------------------------------------------------------
// scale/shift = silu(emb) @ emb_W + emb_b  -> fp32 [B, 2D]   (all fp32)
// ---------------------------------------------------------------------------
__global__ __launch_bounds__(256)
void emb_gemm(const float* __restrict__ emb, const float* __restrict__ W,
              const float* __restrict__ eb, float* __restrict__ ss) {
  int b = blockIdx.x >> 3;
  int n = (blockIdx.x & 7) * 256 + threadIdx.x;
  __shared__ float se[TE_];
  for (int i = threadIdx.x; i < TE_; i += 256) {
    float xv = emb[(size_t)b * TE_ + i];
    se[i] = xv / (1.f + __expf(-xv));
  }
  __syncthreads();
  float acc = 0.f;
  for (int kk = 0; kk < TE_; kk++) acc += se[kk] * W[(size_t)kk * 2048 + n];
  ss[(size_t)b * 2048 + n] = acc + eb[n];
}

// ---------------------------------------------------------------------------
// h_pre = silu( LN(y)*(1+scale) + shift ), vectorized; y bf16, rest fp32
// ---------------------------------------------------------------------------
__global__ __launch_bounds__(256)
void film_rows(const __bf16* __restrict__ y, const float* __restrict__ ss,
               const float* __restrict__ g, const float* __restrict__ bb,
               __bf16* __restrict__ out) {
  size_t row = blockIdx.x;
  int b = (int)(row >> 10);
  int c4 = threadIdx.x * 4;
  bf16x4 yv = *(const bf16x4*)(y + row * D_ + c4);
  float v[4];
  float s = 0.f, s2 = 0.f;
#pragma unroll
  for (int t = 0; t < 4; t++) {
    v[t] = (float)yv[t];
    s += v[t]; s2 += v[t] * v[t];
  }
#pragma unroll
  for (int off = 32; off; off >>= 1) {
    s += __shfl_down(s, off);
    s2 += __shfl_down(s2, off);
  }
  __shared__ float red[8];
  int wave = threadIdx.x >> 6, lane = threadIdx.x & 63;
  if (lane == 0) { red[wave] = s; red[4 + wave] = s2; }
  __syncthreads();
  if (threadIdx.x == 0) {
    float a = 0.f, c = 0.f;
    for (int w = 0; w < 4; w++) { a += red[w]; c += red[4 + w]; }
    red[0] = a; red[4] = c;
  }
  __syncthreads();
  float mu = red[0] / D_;
  float var = red[4] / D_ - mu * mu;
  float rstd = rsqrtf(var + 1e-5f);
  f32x4 gg = *(const f32x4*)(g + c4);
  f32x4 bbv = *(const f32x4*)(bb + c4);
  f32x4 sc = *(const f32x4*)(ss + (size_t)b * 2048 + c4);
  f32x4 sh = *(const f32x4*)(ss + (size_t)b * 2048 + 1024 + c4);
  bf16x4 o;
#pragma unroll
  for (int t = 0; t < 4; t++) {
    float ln = (v[t] - mu) * rstd * gg[t] + bbv[t];
    float hh = ln * (1.f + sc[t]) + sh[t];
    o[t] = (__bf16)(hh / (1.f + __expf(-hh)));
  }
  *(bf16x4*)(out + row * D_ + c4) = o;
}

// ---------------------------------------------------------------------------
extern "C" void kernel_launch(void* const* d_in, const int* in_sizes, int n_in,
                              void* d_out, int out_size, void* d_ws,
                              size_t ws_size, hipStream_t stream) {
  (void)in_sizes; (void)n_in;
  const float* x       = (const float*)d_in[0];
  const float* xf      = (const float*)d_in[1];
  const float* emb     = (const float*)d_in[2];
  const float* norm_g  = (const float*)d_in[3];
  const float* norm_b  = (const float*)d_in[4];
  const float* tnorm_g = (const float*)d_in[5];
  const float* tnorm_b = (const float*)d_in[6];
  const float* Wq      = (const float*)d_in[7];
  const float* bq      = (const float*)d_in[8];
  const float* Wk      = (const float*)d_in[9];
  const float* bk      = (const float*)d_in[10];
  const float* Wv      = (const float*)d_in[11];
  const float* bv      = (const float*)d_in[12];
  const float* emb_W   = (const float*)d_in[13];
  const float* emb_b   = (const float*)d_in[14];
  const float* fnorm_g = (const float*)d_in[15];
  const float* fnorm_b = (const float*)d_in[16];
  const float* out_W   = (const float*)d_in[17];
  const float* out_b   = (const float*)d_in[18];
  float* out = (float*)d_out;

  // -------- workspace layout --------
  const size_t SZ_WQT  = (size_t)D_ * D_ * 2;             // 2 MB   bf16
  const size_t SZ_WKVT = (size_t)2048 * TD_ * 2;          // 3 MB   bf16
  const size_t SZ_XN   = (size_t)B_ * T_ * D_ * 2;        // 64 MB  bf16
  const size_t SZ_XFN  = (size_t)B_ * N_ * TD_ * 2;       // 12 MB  bf16
  const size_t SZ_KV   = (size_t)B_ * N_ * 2048 * 2;      // 32 MB  bf16
  const size_t SZ_BKV  = 2048 * 4;                        // 8 KB   f32
  const size_t NEED = SZ_WQT * 2 + SZ_WKVT + SZ_XN + SZ_XFN + SZ_KV + SZ_BKV;

  if (ws_size < NEED) {  // diagnostic: encode ws_size (MB) into the output
    fill_val<<<(out_size + 255) / 256, 256, 0, stream>>>(
        out, (float)(ws_size >> 20), out_size);
    return;
  }

  char* w = (char*)d_ws;
  __bf16* WqT  = (__bf16*)w; w += SZ_WQT;
  __bf16* WkvT = (__bf16*)w; w += SZ_WKVT;
  __bf16* WoT  = (__bf16*)w; w += SZ_WQT;
  __bf16* xn   = (__bf16*)w; w += SZ_XN;    // later reused as h_pre
  char*   xfnR = w;          w += SZ_XFN;   // xfn; later attn+ss overlay
  __bf16* kvbuf= (__bf16*)w; w += SZ_KV;
  float*  bkv  = (float*)w;  w += SZ_BKV;
  __bf16* xfn  = (__bf16*)xfnR;
  float*  attn = (float*)xfnR;              // alive after xfn dies (8 MB)
  float*  ss   = (float*)(xfnR + (size_t)B_ * H_ * C_ * C_ * 4);
  __bf16* hpre = xn;            // xn dead after q-proj
  __bf16* qbuf = (__bf16*)out;  // q (bf16, 64MB) lives in d_out (128MB f32)
  __bf16* ybuf = qbuf;          // qattn_y works in-place

  // 1. transpose+cast weights to bf16 [N,K]; k and v stacked into WkvT
  transpose_cast<<<dim3(D_ / 32, D_ / 32), dim3(32, 8), 0, stream>>>(Wq, WqT, D_, D_);
  transpose_cast<<<dim3(D_ / 32, TD_ / 32), dim3(32, 8), 0, stream>>>(Wk, WkvT, TD_, D_);
  transpose_cast<<<dim3(D_ / 32, TD_ / 32), dim3(32, 8), 0, stream>>>(
      Wv, WkvT + (size_t)1024 * TD_, TD_, D_);
  transpose_cast<<<dim3(D_ / 32, D_ / 32), dim3(32, 8), 0, stream>>>(out_W, WoT, D_, D_);
  concat2<<<8, 256, 0, stream>>>(bk, bv, bkv);

  // 2. LayerNorms (fp32 in -> bf16 out)
  ln1024<<<B_ * T_, 256, 0, stream>>>(x, norm_g, norm_b, xn);
  ln_rows<<<B_ * N_, 256, 0, stream>>>(xf, tnorm_g, tnorm_b, xfn, TD_);

  // 3. projections (bf16 MFMA, 256^2 two-barrier phases): q, then fused k|v
  gemm256<0, __bf16><<<dim3((B_ * T_ / 256) * (D_ / 256)), 512, 0, stream>>>(
      xn, WqT, bq, nullptr, qbuf, B_ * T_, D_, D_, D_ / 256);
  gemm256<0, __bf16><<<dim3((B_ * N_ / 256) * (2048 / 256)), 512, 0, stream>>>(
      xfn, WkvT, bkv, nullptr, kvbuf, B_ * N_, 2048, TD_, 2048 / 256);

  // 4. attn = softmax_n(k)^T v  (softmax fused; xfn dead -> attn overlays)
  kv_attn<<<B_ * H_, 256, 0, stream>>>(kvbuf, attn);

  // 5. y = softmax_c(q) @ attn  (q softmax fused, in-place in d_out)
  qattn_y<<<dim3(T_ / 64, H_, B_), 256, 0, stream>>>(qbuf, attn, ybuf);

  // 6. FiLM path
  emb_gemm<<<B_ * 8, 256, 0, stream>>>(emb, emb_W, emb_b, ss);
  film_rows<<<B_ * T_, 256, 0, stream>>>(ybuf, ss, fnorm_g, fnorm_b, hpre);

  // 7. out = x + h_pre @ out_W + out_b   (fp32 output + residual)
  gemm256<1, float><<<dim3((B_ * T_ / 256) * (D_ / 256)), 512, 0, stream>>>(
      hpre, WoT, out_b, x, out, B_ * T_, D_, D_, D_ / 256);
}

// Round 4
// 661.440 us; speedup vs baseline: 1.1207x; 1.1207x over previous
//
#include <hip/hip_runtime.h>
#include <hip/hip_bf16.h>
#include <stdint.h>

// Problem constants
#define B_  32
#define T_  1024
#define N_  256
#define D_  1024
#define TD_ 768
#define H_  16
#define C_  64
#define TE_ 2048

typedef __bf16 bf16x8 __attribute__((ext_vector_type(8)));
typedef __bf16 bf16x4 __attribute__((ext_vector_type(4)));
typedef float  f32x4  __attribute__((ext_vector_type(4)));

// async global->LDS, 16B per lane; lds dest must be wave-uniform base (+lane*16)
__device__ __forceinline__ void gll16(const void* g, void* l) {
  __builtin_amdgcn_global_load_lds(
      (const __attribute__((address_space(1))) unsigned int*)g,
      (__attribute__((address_space(3))) unsigned int*)l, 16, 0, 0);
}

// ---------------------------------------------------------------------------
__global__ void fill_val(float* o, float v, int n) {
  int i = blockIdx.x * 256 + threadIdx.x;
  if (i < n) o[i] = v;
}

// ---------------------------------------------------------------------------
// prep_weights: 4 transposes + bias concat fused into ONE launch.
// block dim (32,8). Grid ranges:
//   [0,1024)    Wq  -> WqT              (R=D,  C=D : grid 32x32)
//   [1024,1792) Wk  -> WkvT             (R=TD, C=D : grid 32x24)
//   [1792,2560) Wv  -> WkvT+1024*TD     (R=TD, C=D : grid 32x24)
//   [2560,3584) Wo  -> WoT              (R=D,  C=D : grid 32x32)
//   [3584,3592) concat bk|bv -> bkv
// ---------------------------------------------------------------------------
__device__ __forceinline__ void tc_block(const float* __restrict__ in,
                                         __bf16* __restrict__ out, int R, int C,
                                         int bx, int by) {
  __shared__ float t[32][33];
  int c0 = bx * 32, r0 = by * 32;
  int x = threadIdx.x, y4 = threadIdx.y;
#pragma unroll
  for (int i = 0; i < 4; i++) {
    int rr = y4 * 4 + i;
    t[rr][x] = in[(size_t)(r0 + rr) * C + c0 + x];
  }
  __syncthreads();
#pragma unroll
  for (int i = 0; i < 4; i++) {
    int rr = y4 * 4 + i;
    out[(size_t)(c0 + rr) * R + r0 + x] = (__bf16)t[x][rr];
  }
}

__global__ void prep_weights(const float* __restrict__ Wq,
                             const float* __restrict__ Wk,
                             const float* __restrict__ Wv,
                             const float* __restrict__ Wo,
                             const float* __restrict__ bk,
                             const float* __restrict__ bv,
                             __bf16* __restrict__ WqT, __bf16* __restrict__ WkvT,
                             __bf16* __restrict__ WoT, float* __restrict__ bkv) {
  int bid = blockIdx.x;
  if (bid < 1024) { tc_block(Wq, WqT, D_, D_, bid & 31, bid >> 5); return; }
  bid -= 1024;
  if (bid < 768) { tc_block(Wk, WkvT, TD_, D_, bid & 31, bid >> 5); return; }
  bid -= 768;
  if (bid < 768) {
    tc_block(Wv, WkvT + (size_t)1024 * TD_, TD_, D_, bid & 31, bid >> 5);
    return;
  }
  bid -= 768;
  if (bid < 1024) { tc_block(Wo, WoT, D_, D_, bid & 31, bid >> 5); return; }
  bid -= 1024;
  int i = bid * 256 + threadIdx.y * 32 + threadIdx.x;
  if (i < 1024) bkv[i] = bk[i];
  else if (i < 2048) bkv[i] = bv[i - 1024];
}

// ---------------------------------------------------------------------------
// LayerNorm D=1024, float4 vectorized: thread owns cols tid*4..+3
// ---------------------------------------------------------------------------
__global__ __launch_bounds__(256)
void ln1024(const float* __restrict__ x, const float* __restrict__ g,
            const float* __restrict__ bb, __bf16* __restrict__ out) {
  size_t row = blockIdx.x;
  int c4 = threadIdx.x * 4;
  f32x4 v = *(const f32x4*)(x + row * D_ + c4);
  float s = v[0] + v[1] + v[2] + v[3];
  float s2 = v[0]*v[0] + v[1]*v[1] + v[2]*v[2] + v[3]*v[3];
#pragma unroll
  for (int off = 32; off; off >>= 1) {
    s += __shfl_down(s, off);
    s2 += __shfl_down(s2, off);
  }
  __shared__ float red[8];
  int wave = threadIdx.x >> 6, lane = threadIdx.x & 63;
  if (lane == 0) { red[wave] = s; red[4 + wave] = s2; }
  __syncthreads();
  if (threadIdx.x == 0) {
    float a = 0.f, c = 0.f;
    for (int w = 0; w < 4; w++) { a += red[w]; c += red[4 + w]; }
    red[0] = a; red[4] = c;
  }
  __syncthreads();
  float mu = red[0] / D_;
  float var = red[4] / D_ - mu * mu;
  float rstd = rsqrtf(var + 1e-5f);
  f32x4 gg = *(const f32x4*)(g + c4);
  f32x4 bbv = *(const f32x4*)(bb + c4);
  bf16x4 o;
#pragma unroll
  for (int t = 0; t < 4; t++) o[t] = (__bf16)((v[t] - mu) * rstd * gg[t] + bbv[t]);
  *(bf16x4*)(out + row * D_ + c4) = o;
}

// generic row LN (used for TD=768), scalar
__global__ __launch_bounds__(256)
void ln_rows(const float* __restrict__ x, const float* __restrict__ g,
             const float* __restrict__ bb, __bf16* __restrict__ out, int D) {
  size_t row = blockIdx.x;
  const float* xr = x + row * (size_t)D;
  int tid = threadIdx.x;
  int cnt = D >> 8;
  float v[4];
  float s = 0.f, s2 = 0.f;
  for (int i = 0; i < cnt; i++) {
    float f = xr[tid + i * 256];
    v[i] = f; s += f; s2 += f * f;
  }
#pragma unroll
  for (int off = 32; off; off >>= 1) {
    s += __shfl_down(s, off);
    s2 += __shfl_down(s2, off);
  }
  __shared__ float red[8];
  int wave = tid >> 6, lane = tid & 63;
  if (lane == 0) { red[wave] = s; red[4 + wave] = s2; }
  __syncthreads();
  if (tid == 0) {
    float a = 0.f, c = 0.f;
    for (int w = 0; w < 4; w++) { a += red[w]; c += red[4 + w]; }
    red[0] = a; red[4] = c;
  }
  __syncthreads();
  float mu = red[0] / D;
  float var = red[4] / D - mu * mu;
  float rstd = rsqrtf(var + 1e-5f);
  for (int i = 0; i < cnt; i++) {
    int c = tid + i * 256;
    out[row * (size_t)D + c] = (__bf16)((v[i] - mu) * rstd * g[c] + bb[c]);
  }
}

// ---------------------------------------------------------------------------
// GEMM: C[M,N] = A[M,K](bf16) @ BT[N,K](bf16) + bias(f32)
// 256x256x64 tile, 8 waves (2Mx4N), double-buffered 128KB LDS, two-barrier
// phase windows with counted vmcnt (T2+T3/T4+T5+T1).
//
// R4 ledger (issue spread rebalanced for uniform >=3-phase latency slack):
//   tile t stages for t+1:  P0: B0,B1,B2,B3   P1: A0   P2: A1,A2   P3: A3
//   per-load slack (issue -> gating wait): B0-3: 4 phases, A0: 3, A1: 3,
//   A2: 4, A3: 4  (was 2 phases for A0 in R1/R3 -> tile-boundary stall).
//   Steady end-of-phase waits: e0=6 (gates A1), e1=6 (A2), e2=7 (A3),
//   e3=3 (B0-3'+A0' for next tile). Drain tile: (2,1,0,0).
//
// LDS layout per 64KB buffer: [B tile 32KB][A tile 32KB], row-major
// [256 rows][64 bf16 = 128B], 16B-chunk XOR swizzle: chunk seg' = seg^(row&7)
// applied on the GLOBAL source at stage time (gll16 dest must be linear) and
// identically on the ds_read address -> bank-conflict-free b128 frag reads.
// EPI==1: add residual res(f32). CT = output type (bf16 or float).
// ---------------------------------------------------------------------------
#define WB_(n) asm volatile("s_waitcnt vmcnt(" #n ")" ::: "memory")
#define WB(n) WB_(n)
#define BARR() asm volatile("s_barrier" ::: "memory")
#define LGKM0()                                             \
  do {                                                      \
    asm volatile("s_waitcnt lgkmcnt(0)" ::: "memory");      \
    __builtin_amdgcn_sched_barrier(0);                      \
  } while (0)

template <int EPI, typename CT>
__global__ __launch_bounds__(512, 2)
void gemm256(const __bf16* __restrict__ A, const __bf16* __restrict__ BT,
             const float* __restrict__ bias, const float* __restrict__ res,
             CT* __restrict__ C, int M, int N, int K, int NT) {
  __shared__ char smem[131072];
  const int tid = threadIdx.x;
  const int ln = tid & 63, wv = tid >> 6;

  // T1: bijective XCD swizzle (gridDim.x % 8 == 0 for all our shapes);
  // consecutive swz within an XCD share the same A panel (same m-tile).
  const int nwg = gridDim.x;
  const int swz = (blockIdx.x & 7) * (nwg >> 3) + (blockIdx.x >> 3);
  const int m0 = (swz / NT) * 256, n0 = (swz % NT) * 256;

  const int wm = (wv >> 2) * 128, wn = (wv & 3) * 64;
  const int lr = ln & 15;
  // fragment k-offsets within a 128B row, XOR-swizzled (row&7 == lr&7 for all
  // fragment rows since wm/wn/p*32/ar*16/j*16 are multiples of 8 mod 8 = 0)
  const int xorv = (lr & 7) << 4;
  const int k16 = (ln >> 4) * 16;
  const int koff0 = k16 ^ xorv;          // kk = 0
  const int koff1 = (64 + k16) ^ xorv;   // kk = 1

  // stage source pointers (global side carries the swizzle)
  const int brow = tid >> 3;                       // 0..63 within a B slot
  const int bseg = (tid & 7) ^ (brow & 7);
  const __bf16* Bg = BT + (size_t)(n0 + brow) * K + bseg * 8;
  const int ahalf = tid >> 8, au = tid & 255;
  const int arow = au >> 3;                        // 0..31 within an A slice
  const int aseg = (au & 7) ^ (arow & 7);
  const __bf16* Ag = A + (size_t)(m0 + ahalf * 128 + arow) * K + aseg * 8;

  // wave-uniform LDS stage bases (gll16 adds lane*16)
  char* sBstage = smem + wv * 1024;
  char* sAstage = smem + 32768 + ahalf * 16384 + (wv & 3) * 1024;

  const int nt = K >> 6;  // K-tiles of 64 (16 for K=1024, 12 for K=768)
  f32x4 acc[8][4] = {};
  bf16x8 bfr[4][2], af[2][2];

#define STAGE_B(bf, s, k0) \
  gll16(Bg + (size_t)(s) * 64 * K + (k0), sBstage + (bf) * 65536 + (s) * 8192)
#define STAGE_A(bf, p, k0) \
  gll16(Ag + (size_t)(p) * 32 * K + (k0), sAstage + (bf) * 65536 + (p) * 4096)
#define LDA(pp, ar, kf) \
  (*(const bf16x8*)(sArd + ((wm + (pp) * 32 + (ar) * 16 + lr) * 128) + (kf)))

#define DO_MFMA(pp)                                                          \
  do {                                                                       \
    __builtin_amdgcn_s_setprio(1);                                           \
    _Pragma("unroll") for (int ar = 0; ar < 2; ++ar) {                       \
      _Pragma("unroll") for (int j = 0; j < 4; ++j) {                        \
        acc[(pp) * 2 + ar][j] = __builtin_amdgcn_mfma_f32_16x16x32_bf16(     \
            af[ar][0], bfr[j][0], acc[(pp) * 2 + ar][j], 0, 0, 0);           \
        acc[(pp) * 2 + ar][j] = __builtin_amdgcn_mfma_f32_16x16x32_bf16(     \
            af[ar][1], bfr[j][1], acc[(pp) * 2 + ar][j], 0, 0, 0);           \
      }                                                                      \
    }                                                                        \
    __builtin_amdgcn_s_setprio(0);                                           \
    __builtin_amdgcn_sched_barrier(0);                                       \
  } while (0)

#define TILE(buf, kst, PF, e0, e1, e2, e3)                                   \
  do {                                                                       \
    const char* sBrd = smem + (buf) * 65536;                                 \
    const char* sArd = sBrd + 32768;                                         \
    /* ---- P0: stage all B for t+1 ---- */                                  \
    if (PF) {                                                                \
      STAGE_B((buf) ^ 1, 0, kst); STAGE_B((buf) ^ 1, 1, kst);                \
      STAGE_B((buf) ^ 1, 2, kst); STAGE_B((buf) ^ 1, 3, kst);                \
    }                                                                        \
    _Pragma("unroll") for (int j = 0; j < 4; ++j) {                          \
      bfr[j][0] = *(const bf16x8*)(sBrd + (wn + j * 16 + lr) * 128 + koff0); \
      bfr[j][1] = *(const bf16x8*)(sBrd + (wn + j * 16 + lr) * 128 + koff1); \
    }                                                                        \
    af[0][0] = LDA(0, 0, koff0); af[0][1] = LDA(0, 0, koff1);                \
    af[1][0] = LDA(0, 1, koff0); af[1][1] = LDA(0, 1, koff1);                \
    BARR(); LGKM0();                                                         \
    DO_MFMA(0);                                                              \
    WB(e0); BARR();                                                          \
    /* ---- P1: stage A0 ---- */                                             \
    if (PF) { STAGE_A((buf) ^ 1, 0, kst); }                                  \
    af[0][0] = LDA(1, 0, koff0); af[0][1] = LDA(1, 0, koff1);                \
    af[1][0] = LDA(1, 1, koff0); af[1][1] = LDA(1, 1, koff1);                \
    BARR(); LGKM0();                                                         \
    DO_MFMA(1);                                                              \
    WB(e1); BARR();                                                          \
    /* ---- P2: stage A1,A2 ---- */                                          \
    if (PF) { STAGE_A((buf) ^ 1, 1, kst); STAGE_A((buf) ^ 1, 2, kst); }      \
    af[0][0] = LDA(2, 0, koff0); af[0][1] = LDA(2, 0, koff1);                \
    af[1][0] = LDA(2, 1, koff0); af[1][1] = LDA(2, 1, koff1);                \
    BARR(); LGKM0();                                                         \
    DO_MFMA(2);                                                              \
    WB(e2); BARR();                                                          \
    /* ---- P3: stage A3 ---- */                                             \
    if (PF) { STAGE_A((buf) ^ 1, 3, kst); }                                  \
    af[0][0] = LDA(3, 0, koff0); af[0][1] = LDA(3, 0, koff1);                \
    af[1][0] = LDA(3, 1, koff0); af[1][1] = LDA(3, 1, koff1);                \
    BARR(); LGKM0();                                                         \
    DO_MFMA(3);                                                              \
    WB(e3); BARR();                                                          \
  } while (0)

  // prologue: stage tile 0 into buf 0 (same issue order as steady state)
  STAGE_B(0, 0, 0); STAGE_B(0, 1, 0); STAGE_B(0, 2, 0); STAGE_B(0, 3, 0);
  STAGE_A(0, 0, 0); STAGE_A(0, 1, 0); STAGE_A(0, 2, 0); STAGE_A(0, 3, 0);
  WB(3); BARR();

  int kst = 64;
  const int npair = (nt >> 1) - 1;
  for (int tt = 0; tt < npair; ++tt) {
    TILE(0, kst, 1, 6, 6, 7, 3); kst += 64;
    TILE(1, kst, 1, 6, 6, 7, 3); kst += 64;
  }
  TILE(0, kst, 1, 6, 6, 7, 3);   // tile nt-2 stages tile nt-1
  TILE(1, 0, 0, 2, 1, 0, 0);     // tile nt-1, no prefetch, drain

#undef TILE
#undef DO_MFMA
#undef LDA
#undef STAGE_A
#undef STAGE_B

  // ---- epilogue: per-wave-private LDS re-swizzle, coalesced 16B stores.
  // C/D layout: col = lane&15, row = (lane>>4)*4 + reg   [m89-verified]
  __syncthreads();
  float* scratch = (float*)smem + wv * 1088;  // 16 rows x 68 fp32 (16B-aligned)
  const int qd = ln >> 4;
#pragma unroll
  for (int i = 0; i < 8; ++i) {
#pragma unroll
    for (int j = 0; j < 4; ++j)
#pragma unroll
      for (int r = 0; r < 4; ++r)
        scratch[(qd * 4 + r) * 68 + j * 16 + lr] = acc[i][j][r];
    asm volatile("s_waitcnt lgkmcnt(0)" ::: "memory");
#pragma unroll
    for (int s = 0; s < 4; ++s) {
      int rr = qd + 4 * s;
      f32x4 vv = *(f32x4*)&scratch[rr * 68 + lr * 4];
      int row = m0 + wm + i * 16 + rr;
      int col = n0 + wn + lr * 4;
      size_t idx = (size_t)row * N + col;
      vv += *(const f32x4*)&bias[col];
      if (EPI == 1) vv += *(const f32x4*)&res[idx];
      if constexpr (sizeof(CT) == 4) {
        *(f32x4*)&C[idx] = vv;
      } else {
        bf16x4 o;
#pragma unroll
        for (int t2 = 0; t2 < 4; ++t2) o[t2] = (__bf16)vv[t2];
        *(bf16x4*)&C[idx] = o;
      }
    }
    asm volatile("s_waitcnt lgkmcnt(0)" ::: "memory");
  }
}

// ---------------------------------------------------------------------------
// attn[b,h,c,d] = sum_n softmax_n(k)[n,c] * v[n,d], softmax fused.
// kv: [B, N, 2048] bf16, k = cols h*64.. , v = cols 1024+h*64..
// R4: V chunk 64 rows (16 KB) -> 8 barriers instead of 16.
// ---------------------------------------------------------------------------
__global__ __launch_bounds__(256)
void kv_attn(const __bf16* __restrict__ kv, float* __restrict__ attn) {
  int h = blockIdx.x & 15, b = blockIdx.x >> 4;
  __shared__ __bf16 sK[256 * 72];  // [n][c], stride 72 (144B, 16B-aligned rows)
  __shared__ float sV[64 * 64];    // 16 KB chunk
  __shared__ float sInv[64];
  int tid = threadIdx.x;
  const __bf16* kb = kv + (size_t)b * N_ * 2048 + h * C_;
  const __bf16* vb = kb + 1024;

  // stage all of k: thread t loads row t (64 bf16)
  {
    const __bf16* src = kb + (size_t)tid * 2048;
#pragma unroll
    for (int j = 0; j < 8; j++)
      *(bf16x8*)&sK[tid * 72 + j * 8] = *(const bf16x8*)(src + j * 8);
  }
  __syncthreads();

  // per-column softmax stats: 4 threads per column c, each covers 64 n's
  {
    int c = tid >> 2, qq = tid & 3;
    float m = -1e30f;
    for (int t = 0; t < 64; t++)
      m = fmaxf(m, (float)sK[(qq * 64 + t) * 72 + c]);
    m = fmaxf(m, __shfl_xor(m, 1));
    m = fmaxf(m, __shfl_xor(m, 2));
    float s = 0.f;
    for (int t = 0; t < 64; t++) {
      int idx = (qq * 64 + t) * 72 + c;
      float e = __expf((float)sK[idx] - m);
      sK[idx] = (__bf16)e;
      s += e;
    }
    s += __shfl_xor(s, 1);
    s += __shfl_xor(s, 2);
    if (qq == 0) sInv[c] = 1.f / s;
  }
  __syncthreads();

  int c0 = (tid & 15) * 4, d0 = (tid >> 4) * 4;
  float acc[4][4] = {};
  for (int n0 = 0; n0 < N_; n0 += 64) {
    __syncthreads();
    {
      int r = tid >> 2, s8 = (tid & 3) * 16;
      const __bf16* vr = vb + (size_t)(n0 + r) * 2048 + s8;
      bf16x8 a0 = *(const bf16x8*)vr;
      bf16x8 a1 = *(const bf16x8*)(vr + 8);
#pragma unroll
      for (int j = 0; j < 8; j++) {
        sV[r * 64 + s8 + j] = (float)a0[j];
        sV[r * 64 + s8 + 8 + j] = (float)a1[j];
      }
    }
    __syncthreads();
    for (int n = 0; n < 64; n++) {
      bf16x4 kk = *(const bf16x4*)&sK[(n0 + n) * 72 + c0];
      f32x4 vd = *(const f32x4*)&sV[n * 64 + d0];
#pragma unroll
      for (int i = 0; i < 4; i++) {
        float kf = (float)kk[i];
#pragma unroll
        for (int j = 0; j < 4; j++) acc[i][j] += kf * vd[j];
      }
    }
  }
  float* ab = attn + (size_t)(b * H_ + h) * 4096;
#pragma unroll
  for (int i = 0; i < 4; i++) {
    float inv = sInv[c0 + i];
    f32x4 o;
#pragma unroll
    for (int j = 0; j < 4; j++) o[j] = acc[i][j] * inv;
    *(f32x4*)&ab[(c0 + i) * 64 + d0] = o;
  }
}

// ---------------------------------------------------------------------------
// y[b,t,h,:] = softmax_c(q[b,t,h,:]) @ attn[b,h]   (channel softmax fused)
// In-place safe (y aliases q): q tile fully staged to LDS before writes.
// ---------------------------------------------------------------------------
__global__ __launch_bounds__(256)
void qattn_y(const __bf16* __restrict__ q, const float* __restrict__ attn,
             __bf16* __restrict__ y) {
  int tt = blockIdx.x * 64;
  int h = blockIdx.y, b = blockIdx.z;
  __shared__ float sQ[64 * 65];  // [c][r], stride 65
  __shared__ float sA[64 * 64];  // [c][d]
  int tid = threadIdx.x;
  const __bf16* qb = q + ((size_t)b * T_ + tt) * D_ + h * C_;
#pragma unroll
  for (int it = 0; it < 2; it++) {
    int r = (tid >> 3) + it * 32;
    int cc = (tid & 7) * 8;
    bf16x8 vv = *(const bf16x8*)(qb + (size_t)r * D_ + cc);
#pragma unroll
    for (int j = 0; j < 8; j++) sQ[(cc + j) * 65 + r] = (float)vv[j];
  }
  const float* ab = attn + (size_t)(b * H_ + h) * 4096;
  for (int i = tid; i < 1024; i += 256) ((f32x4*)sA)[i] = ((const f32x4*)ab)[i];
  __syncthreads();
  // softmax over c per row r: 4 threads/row, each covers 16 c's
  {
    int r = tid >> 2, sub = tid & 3;
    float m = -1e30f;
#pragma unroll
    for (int j = 0; j < 16; j++)
      m = fmaxf(m, sQ[(sub * 16 + j) * 65 + r]);
    m = fmaxf(m, __shfl_xor(m, 1));
    m = fmaxf(m, __shfl_xor(m, 2));
    float s = 0.f;
#pragma unroll
    for (int j = 0; j < 16; j++) {
      int idx = (sub * 16 + j) * 65 + r;
      float e = __expf(sQ[idx] - m);
      sQ[idx] = e;
      s += e;
    }
    s += __shfl_xor(s, 1);
    s += __shfl_xor(s, 2);
    float inv = 1.f / s;
#pragma unroll
    for (int j = 0; j < 16; j++) sQ[(sub * 16 + j) * 65 + r] *= inv;
  }
  __syncthreads();
  int r0 = (tid >> 4) * 4, d0 = (tid & 15) * 4;
  float acc[4][4] = {};
  for (int c = 0; c < 64; c++) {
    f32x4 qv = *(const f32x4*)&sQ[c * 65 + r0];
    f32x4 av = *(const f32x4*)&sA[c * 64 + d0];
#pragma unroll
    for (int i = 0; i < 4; i++)
#pragma unroll
      for (int j = 0; j < 4; j++) acc[i][j] += qv[i] * av[j];
  }
  __bf16* yb = y + ((size_t)b * T_ + tt) * D_ + h * C_;
#pragma unroll
  for (int i = 0; i < 4; i++) {
    bf16x4 o;
#pragma unroll
    for (int j = 0; j < 4; j++) o[j] = (__bf16)acc[i][j];
    *(bf16x4*)(yb + (size_t)(r0 + i) * D_ + d0) = o;
  }
}

// ---------------------------------------------------------------------------
// FiLM scale/shift = silu(emb) @ emb_W + emb_b -> fp32 [B, 2D]
// R4: ss_init writes the bias, emb_gemm is 4-way K-split with atomicAdd
// (1024 blocks, 4 blocks/CU vs the old 1 block/CU serial-K chain).
// ---------------------------------------------------------------------------
__global__ __launch_bounds__(256)
void ss_init(const float* __restrict__ eb, float* __restrict__ ss) {
  int i = blockIdx.x * 256 + threadIdx.x;  // grid 256 -> 65536 = 32*2048
  ss[i] = eb[i & 2047];
}

__global__ __launch_bounds__(256)
void emb_gemm(const float* __restrict__ emb, const float* __restrict__ W,
              float* __restrict__ ss) {
  int b  = blockIdx.x >> 5;
  int nc = (blockIdx.x >> 2) & 7;
  int kq = blockIdx.x & 3;
  __shared__ float se[512];
  int k0 = kq * 512;
  for (int i = threadIdx.x; i < 512; i += 256) {
    float xv = emb[(size_t)b * TE_ + k0 + i];
    se[i] = xv / (1.f + __expf(-xv));
  }
  __syncthreads();
  int n = nc * 256 + threadIdx.x;
  float acc = 0.f;
  for (int kk = 0; kk < 512; kk++) acc += se[kk] * W[(size_t)(k0 + kk) * 2048 + n];
  atomicAdd(&ss[(size_t)b * 2048 + n], acc);
}

// ---------------------------------------------------------------------------
// h_pre = silu( LN(y)*(1+scale) + shift ), vectorized; y bf16, rest fp32
// ---------------------------------------------------------------------------
__global__ __launch_bounds__(256)
void film_rows(const __bf16* __restrict__ y, const float* __restrict__ ss,
               const float* __restrict__ g, const float* __restrict__ bb,
               __bf16* __restrict__ out) {
  size_t row = blockIdx.x;
  int b = (int)(row >> 10);
  int c4 = threadIdx.x * 4;
  bf16x4 yv = *(const bf16x4*)(y + row * D_ + c4);
  float v[4];
  float s = 0.f, s2 = 0.f;
#pragma unroll
  for (int t = 0; t < 4; t++) {
    v[t] = (float)yv[t];
    s += v[t]; s2 += v[t] * v[t];
  }
#pragma unroll
  for (int off = 32; off; off >>= 1) {
    s += __shfl_down(s, off);
    s2 += __shfl_down(s2, off);
  }
  __shared__ float red[8];
  int wave = threadIdx.x >> 6, lane = threadIdx.x & 63;
  if (lane == 0) { red[wave] = s; red[4 + wave] = s2; }
  __syncthreads();
  if (threadIdx.x == 0) {
    float a = 0.f, c = 0.f;
    for (int w = 0; w < 4; w++) { a += red[w]; c += red[4 + w]; }
    red[0] = a; red[4] = c;
  }
  __syncthreads();
  float mu = red[0] / D_;
  float var = red[4] / D_ - mu * mu;
  float rstd = rsqrtf(var + 1e-5f);
  f32x4 gg = *(const f32x4*)(g + c4);
  f32x4 bbv = *(const f32x4*)(bb + c4);
  f32x4 sc = *(const f32x4*)(ss + (size_t)b * 2048 + c4);
  f32x4 sh = *(const f32x4*)(ss + (size_t)b * 2048 + 1024 + c4);
  bf16x4 o;
#pragma unroll
  for (int t = 0; t < 4; t++) {
    float ln = (v[t] - mu) * rstd * gg[t] + bbv[t];
    float hh = ln * (1.f + sc[t]) + sh[t];
    o[t] = (__bf16)(hh / (1.f + __expf(-hh)));
  }
  *(bf16x4*)(out + row * D_ + c4) = o;
}

// ---------------------------------------------------------------------------
extern "C" void kernel_launch(void* const* d_in, const int* in_sizes, int n_in,
                              void* d_out, int out_size, void* d_ws,
                              size_t ws_size, hipStream_t stream) {
  (void)in_sizes; (void)n_in;
  const float* x       = (const float*)d_in[0];
  const float* xf      = (const float*)d_in[1];
  const float* emb     = (const float*)d_in[2];
  const float* norm_g  = (const float*)d_in[3];
  const float* norm_b  = (const float*)d_in[4];
  const float* tnorm_g = (const float*)d_in[5];
  const float* tnorm_b = (const float*)d_in[6];
  const float* Wq      = (const float*)d_in[7];
  const float* bq      = (const float*)d_in[8];
  const float* Wk      = (const float*)d_in[9];
  const float* bk      = (const float*)d_in[10];
  const float* Wv      = (const float*)d_in[11];
  const float* bv      = (const float*)d_in[12];
  const float* emb_W   = (const float*)d_in[13];
  const float* emb_b   = (const float*)d_in[14];
  const float* fnorm_g = (const float*)d_in[15];
  const float* fnorm_b = (const float*)d_in[16];
  const float* out_W   = (const float*)d_in[17];
  const float* out_b   = (const float*)d_in[18];
  float* out = (float*)d_out;

  // -------- workspace layout --------
  const size_t SZ_WQT  = (size_t)D_ * D_ * 2;             // 2 MB   bf16
  const size_t SZ_WKVT = (size_t)2048 * TD_ * 2;          // 3 MB   bf16
  const size_t SZ_XN   = (size_t)B_ * T_ * D_ * 2;        // 64 MB  bf16
  const size_t SZ_XFN  = (size_t)B_ * N_ * TD_ * 2;       // 12 MB  bf16
  const size_t SZ_KV   = (size_t)B_ * N_ * 2048 * 2;      // 32 MB  bf16
  const size_t SZ_BKV  = 2048 * 4;                        // 8 KB   f32
  const size_t NEED = SZ_WQT * 2 + SZ_WKVT + SZ_XN + SZ_XFN + SZ_KV + SZ_BKV;

  if (ws_size < NEED) {  // diagnostic: encode ws_size (MB) into the output
    fill_val<<<(out_size + 255) / 256, 256, 0, stream>>>(
        out, (float)(ws_size >> 20), out_size);
    return;
  }

  char* w = (char*)d_ws;
  __bf16* WqT  = (__bf16*)w; w += SZ_WQT;
  __bf16* WkvT = (__bf16*)w; w += SZ_WKVT;
  __bf16* WoT  = (__bf16*)w; w += SZ_WQT;
  __bf16* xn   = (__bf16*)w; w += SZ_XN;    // later reused as h_pre
  char*   xfnR = w;          w += SZ_XFN;   // xfn; later attn+ss overlay
  __bf16* kvbuf= (__bf16*)w; w += SZ_KV;
  float*  bkv  = (float*)w;  w += SZ_BKV;
  __bf16* xfn  = (__bf16*)xfnR;
  float*  attn = (float*)xfnR;              // alive after xfn dies (8 MB)
  float*  ss   = (float*)(xfnR + (size_t)B_ * H_ * C_ * C_ * 4);
  __bf16* hpre = xn;            // xn dead after q-proj
  __bf16* qbuf = (__bf16*)out;  // q (bf16, 64MB) lives in d_out (128MB f32)
  __bf16* ybuf = qbuf;          // qattn_y works in-place

  // 1. weight transposes + bias concat, one launch
  prep_weights<<<3592, dim3(32, 8), 0, stream>>>(Wq, Wk, Wv, out_W, bk, bv,
                                                 WqT, WkvT, WoT, bkv);

  // 2. LayerNorms (fp32 in -> bf16 out)
  ln1024<<<B_ * T_, 256, 0, stream>>>(x, norm_g, norm_b, xn);
  ln_rows<<<B_ * N_, 256, 0, stream>>>(xf, tnorm_g, tnorm_b, xfn, TD_);

  // 3. projections (bf16 MFMA, 256^2 two-barrier phases): q, then fused k|v
  gemm256<0, __bf16><<<dim3((B_ * T_ / 256) * (D_ / 256)), 512, 0, stream>>>(
      xn, WqT, bq, nullptr, qbuf, B_ * T_, D_, D_, D_ / 256);
  gemm256<0, __bf16><<<dim3((B_ * N_ / 256) * (2048 / 256)), 512, 0, stream>>>(
      xfn, WkvT, bkv, nullptr, kvbuf, B_ * N_, 2048, TD_, 2048 / 256);

  // 4. attn = softmax_n(k)^T v  (softmax fused; xfn dead -> attn overlays)
  kv_attn<<<B_ * H_, 256, 0, stream>>>(kvbuf, attn);

  // 5. y = softmax_c(q) @ attn  (q softmax fused, in-place in d_out)
  qattn_y<<<dim3(T_ / 64, H_, B_), 256, 0, stream>>>(qbuf, attn, ybuf);

  // 6. FiLM path (ss = eb, then 4-way K-split atomic accumulate)
  ss_init<<<256, 256, 0, stream>>>(emb_b, ss);
  emb_gemm<<<B_ * 32, 256, 0, stream>>>(emb, emb_W, ss);
  film_rows<<<B_ * T_, 256, 0, stream>>>(ybuf, ss, fnorm_g, fnorm_b, hpre);

  // 7. out = x + h_pre @ out_W + out_b   (fp32 output + residual)
  gemm256<1, float><<<dim3((B_ * T_ / 256) * (D_ / 256)), 512, 0, stream>>>(
      hpre, WoT, out_b, x, out, B_ * T_, D_, D_, D_ / 256);
}

// Round 5
// 637.365 us; speedup vs baseline: 1.1630x; 1.0378x over previous
//
#include <hip/hip_runtime.h>
#include <hip/hip_bf16.h>
#include <stdint.h>

// Problem constants
#define B_  32
#define T_  1024
#define N_  256
#define D_  1024
#define TD_ 768
#define H_  16
#define C_  64
#define TE_ 2048

typedef __bf16 bf16x8 __attribute__((ext_vector_type(8)));
typedef __bf16 bf16x4 __attribute__((ext_vector_type(4)));
typedef float  f32x4  __attribute__((ext_vector_type(4)));

// async global->LDS, 16B per lane; lds dest must be wave-uniform base (+lane*16)
__device__ __forceinline__ void gll16(const void* g, void* l) {
  __builtin_amdgcn_global_load_lds(
      (const __attribute__((address_space(1))) unsigned int*)g,
      (__attribute__((address_space(3))) unsigned int*)l, 16, 0, 0);
}

// ---------------------------------------------------------------------------
__global__ void fill_val(float* o, float v, int n) {
  int i = blockIdx.x * 256 + threadIdx.x;
  if (i < n) o[i] = v;
}

// ---------------------------------------------------------------------------
// preprocess: ONE launch for all input-only work (block-ID ranges):
//   [0,1024)        Wq  -> WqT   (32x32 transpose tiles)
//   [1024,1792)     Wk  -> WkvT
//   [1792,2560)     Wv  -> WkvT + 1024*TD
//   [2560,3584)     Wo  -> WoT
//   [3584,3592)     concat bk|bv -> bkv
//   [3592,+32768)   ln1024 of x -> xn (bf16)
//   [.. ,+8192)     ln768 of xf -> xfn (bf16)
//   [.. ,+256)      ss = broadcast emb_b
// All segments independent (write disjoint buffers, read only inputs).
// ---------------------------------------------------------------------------
__device__ __forceinline__ void tc_block(const float* __restrict__ in,
                                         __bf16* __restrict__ out, int R, int C,
                                         int bx, int by, int x, int y4,
                                         float (*t)[33]) {
  int c0 = bx * 32, r0 = by * 32;
#pragma unroll
  for (int i = 0; i < 4; i++) {
    int rr = y4 * 4 + i;
    t[rr][x] = in[(size_t)(r0 + rr) * C + c0 + x];
  }
  __syncthreads();
#pragma unroll
  for (int i = 0; i < 4; i++) {
    int rr = y4 * 4 + i;
    out[(size_t)(c0 + rr) * R + r0 + x] = (__bf16)t[x][rr];
  }
}

__global__ __launch_bounds__(256)
void preprocess(const float* __restrict__ Wq, const float* __restrict__ Wk,
                const float* __restrict__ Wv, const float* __restrict__ Wo,
                const float* __restrict__ bk, const float* __restrict__ bv,
                const float* __restrict__ x, const float* __restrict__ ng,
                const float* __restrict__ nb, const float* __restrict__ xf,
                const float* __restrict__ tg, const float* __restrict__ tb,
                const float* __restrict__ eb,
                __bf16* __restrict__ WqT, __bf16* __restrict__ WkvT,
                __bf16* __restrict__ WoT, float* __restrict__ bkv,
                __bf16* __restrict__ xn, __bf16* __restrict__ xfn,
                float* __restrict__ ss) {
  __shared__ float t[32][33];
  __shared__ float red[8];
  int bid = blockIdx.x, tid = threadIdx.x;
  int xq = tid & 31, y4 = tid >> 5;

  if (bid < 1024) { tc_block(Wq, WqT, D_, D_, bid & 31, bid >> 5, xq, y4, t); return; }
  bid -= 1024;
  if (bid < 768) { tc_block(Wk, WkvT, TD_, D_, bid & 31, bid >> 5, xq, y4, t); return; }
  bid -= 768;
  if (bid < 768) {
    tc_block(Wv, WkvT + (size_t)1024 * TD_, TD_, D_, bid & 31, bid >> 5, xq, y4, t);
    return;
  }
  bid -= 768;
  if (bid < 1024) { tc_block(Wo, WoT, D_, D_, bid & 31, bid >> 5, xq, y4, t); return; }
  bid -= 1024;
  if (bid < 8) {
    int i = bid * 256 + tid;
    if (i < 1024) bkv[i] = bk[i];
    else bkv[i] = bv[i - 1024];
    return;
  }
  bid -= 8;
  if (bid < 32768) {
    // ---- ln1024: row = bid, thread owns cols tid*4..+3
    size_t row = bid;
    int c4 = tid * 4;
    f32x4 v = *(const f32x4*)(x + row * D_ + c4);
    float s = v[0] + v[1] + v[2] + v[3];
    float s2 = v[0]*v[0] + v[1]*v[1] + v[2]*v[2] + v[3]*v[3];
#pragma unroll
    for (int off = 32; off; off >>= 1) {
      s += __shfl_down(s, off);
      s2 += __shfl_down(s2, off);
    }
    int wave = tid >> 6, lane = tid & 63;
    if (lane == 0) { red[wave] = s; red[4 + wave] = s2; }
    __syncthreads();
    if (tid == 0) {
      float a = 0.f, c = 0.f;
      for (int w = 0; w < 4; w++) { a += red[w]; c += red[4 + w]; }
      red[0] = a; red[4] = c;
    }
    __syncthreads();
    float mu = red[0] / D_;
    float var = red[4] / D_ - mu * mu;
    float rstd = rsqrtf(var + 1e-5f);
    f32x4 gg = *(const f32x4*)(ng + c4);
    f32x4 bbv = *(const f32x4*)(nb + c4);
    bf16x4 o;
#pragma unroll
    for (int q = 0; q < 4; q++) o[q] = (__bf16)((v[q] - mu) * rstd * gg[q] + bbv[q]);
    *(bf16x4*)(xn + row * D_ + c4) = o;
    return;
  }
  bid -= 32768;
  if (bid < 8192) {
    // ---- ln768: row = bid, scalar x3
    size_t row = bid;
    const float* xr = xf + row * (size_t)TD_;
    float v[3];
    float s = 0.f, s2 = 0.f;
#pragma unroll
    for (int i = 0; i < 3; i++) {
      float f = xr[tid + i * 256];
      v[i] = f; s += f; s2 += f * f;
    }
#pragma unroll
    for (int off = 32; off; off >>= 1) {
      s += __shfl_down(s, off);
      s2 += __shfl_down(s2, off);
    }
    int wave = tid >> 6, lane = tid & 63;
    if (lane == 0) { red[wave] = s; red[4 + wave] = s2; }
    __syncthreads();
    if (tid == 0) {
      float a = 0.f, c = 0.f;
      for (int w = 0; w < 4; w++) { a += red[w]; c += red[4 + w]; }
      red[0] = a; red[4] = c;
    }
    __syncthreads();
    float mu = red[0] / TD_;
    float var = red[4] / TD_ - mu * mu;
    float rstd = rsqrtf(var + 1e-5f);
#pragma unroll
    for (int i = 0; i < 3; i++) {
      int c = tid + i * 256;
      xfn[row * (size_t)TD_ + c] = (__bf16)((v[i] - mu) * rstd * tg[c] + tb[c]);
    }
    return;
  }
  bid -= 8192;
  {  // ss init: 256 blocks -> 65536 = 32*2048
    int i = bid * 256 + tid;
    ss[i] = eb[i & 2047];
  }
}

// ---------------------------------------------------------------------------
// GEMM body: C[M,N] = A[M,K](bf16) @ BT[N,K](bf16) + bias(f32), N = NT*256.
// 256x256x64 tile, 8 waves (2Mx4N), double-buffered 128KB LDS, R1-best
// schedule: per-phase SYNCV(w) = {sched_barrier; vmcnt(w); s_barrier}, then
// 2 stage gll16, ds_reads, 16 MFMA (setprio-wrapped).
// Stage spread P0:B0,B1 P1:B2,B3 P2:A0,A1 P3:A2,A3; steady waits (3,4,5,6),
// drain tile (3,2,1,0). Ledger verified: oldest-done counts cover each
// phase's fragment slice exactly.
//
// LDS per 64KB buffer: [B 32KB][A 32KB], rows of 128B, 16B-chunk XOR swizzle
// seg' = seg^(row&7) applied on the GLOBAL source (gll16 dest linear) and on
// the ds_read address -> conflict-free b128 reads.
// EPI==1: add residual res(f32). CT = output type (bf16 or float).
// ---------------------------------------------------------------------------
#define SYNCV_(n)                                                  \
  do {                                                             \
    __builtin_amdgcn_sched_barrier(0);                             \
    asm volatile("s_waitcnt vmcnt(" #n ")\n\ts_barrier" ::: "memory"); \
  } while (0)
#define SYNCV(n) SYNCV_(n)

template <int EPI, typename CT>
__device__ __forceinline__ void gemm_body(char* smem,
    const __bf16* __restrict__ A, const __bf16* __restrict__ BT,
    const float* __restrict__ bias, const float* __restrict__ res,
    CT* __restrict__ C, int K, int NT, int bid, int nwg) {
  const int tid = threadIdx.x;
  const int ln = tid & 63, wv = tid >> 6;
  const int N = NT << 8;

  // T1: bijective XCD swizzle (nwg % 8 == 0 for all our shapes)
  const int swz = (bid & 7) * (nwg >> 3) + (bid >> 3);
  const int m0 = (swz / NT) * 256, n0 = (swz % NT) * 256;

  const int wm = (wv >> 2) * 128, wn = (wv & 3) * 64;
  const int lr = ln & 15;
  const int xorv = (lr & 7) << 4;
  const int k16 = (ln >> 4) * 16;
  const int koff0 = k16 ^ xorv;          // kk = 0
  const int koff1 = (64 + k16) ^ xorv;   // kk = 1

  // stage source pointers (global side carries the swizzle)
  const int brow = tid >> 3;
  const int bseg = (tid & 7) ^ (brow & 7);
  const __bf16* Bg = BT + (size_t)(n0 + brow) * K + bseg * 8;
  const int ahalf = tid >> 8, au = tid & 255;
  const int arow = au >> 3;
  const int aseg = (au & 7) ^ (arow & 7);
  const __bf16* Ag = A + (size_t)(m0 + ahalf * 128 + arow) * K + aseg * 8;

  // wave-uniform LDS stage bases (gll16 adds lane*16)
  char* sBstage = smem + wv * 1024;
  char* sAstage = smem + 32768 + ahalf * 16384 + (wv & 3) * 1024;

  const int nt = K >> 6;
  f32x4 acc[8][4] = {};
  bf16x8 bfr[4][2], af[2][2];

#define STAGE_B(bf, s, k0) \
  gll16(Bg + (size_t)(s) * 64 * K + (k0), sBstage + (bf) * 65536 + (s) * 8192)
#define STAGE_A(bf, p, k0) \
  gll16(Ag + (size_t)(p) * 32 * K + (k0), sAstage + (bf) * 65536 + (p) * 4096)
#define LDA(pp, ar, kf) \
  (*(const bf16x8*)(sArd + ((wm + (pp) * 32 + (ar) * 16 + lr) * 128) + (kf)))

#define DO_MFMA(pp)                                                          \
  do {                                                                       \
    __builtin_amdgcn_s_setprio(1);                                           \
    _Pragma("unroll") for (int ar = 0; ar < 2; ++ar) {                       \
      _Pragma("unroll") for (int j = 0; j < 4; ++j) {                        \
        acc[(pp) * 2 + ar][j] = __builtin_amdgcn_mfma_f32_16x16x32_bf16(     \
            af[ar][0], bfr[j][0], acc[(pp) * 2 + ar][j], 0, 0, 0);           \
        acc[(pp) * 2 + ar][j] = __builtin_amdgcn_mfma_f32_16x16x32_bf16(     \
            af[ar][1], bfr[j][1], acc[(pp) * 2 + ar][j], 0, 0, 0);           \
      }                                                                      \
    }                                                                        \
    __builtin_amdgcn_s_setprio(0);                                           \
  } while (0)

#define TILE(buf, kst, PF, w0, w1, w2, w3)                                   \
  do {                                                                       \
    const char* sBrd = smem + (buf) * 65536;                                 \
    const char* sArd = sBrd + 32768;                                         \
    SYNCV(w0);                                                               \
    if (PF) { STAGE_B((buf) ^ 1, 0, kst); STAGE_B((buf) ^ 1, 1, kst); }      \
    _Pragma("unroll") for (int j = 0; j < 4; ++j) {                          \
      bfr[j][0] = *(const bf16x8*)(sBrd + (wn + j * 16 + lr) * 128 + koff0); \
      bfr[j][1] = *(const bf16x8*)(sBrd + (wn + j * 16 + lr) * 128 + koff1); \
    }                                                                        \
    af[0][0] = LDA(0, 0, koff0); af[0][1] = LDA(0, 0, koff1);                \
    af[1][0] = LDA(0, 1, koff0); af[1][1] = LDA(0, 1, koff1);                \
    DO_MFMA(0);                                                              \
    SYNCV(w1);                                                               \
    if (PF) { STAGE_B((buf) ^ 1, 2, kst); STAGE_B((buf) ^ 1, 3, kst); }      \
    af[0][0] = LDA(1, 0, koff0); af[0][1] = LDA(1, 0, koff1);                \
    af[1][0] = LDA(1, 1, koff0); af[1][1] = LDA(1, 1, koff1);                \
    DO_MFMA(1);                                                              \
    SYNCV(w2);                                                               \
    if (PF) { STAGE_A((buf) ^ 1, 0, kst); STAGE_A((buf) ^ 1, 1, kst); }      \
    af[0][0] = LDA(2, 0, koff0); af[0][1] = LDA(2, 0, koff1);                \
    af[1][0] = LDA(2, 1, koff0); af[1][1] = LDA(2, 1, koff1);                \
    DO_MFMA(2);                                                              \
    SYNCV(w3);                                                               \
    if (PF) { STAGE_A((buf) ^ 1, 2, kst); STAGE_A((buf) ^ 1, 3, kst); }      \
    af[0][0] = LDA(3, 0, koff0); af[0][1] = LDA(3, 0, koff1);                \
    af[1][0] = LDA(3, 1, koff0); af[1][1] = LDA(3, 1, koff1);                \
    DO_MFMA(3);                                                              \
  } while (0)

  // prologue: stage tile 0 into buf 0 (B first, then A)
  STAGE_B(0, 0, 0); STAGE_B(0, 1, 0); STAGE_B(0, 2, 0); STAGE_B(0, 3, 0);
  STAGE_A(0, 0, 0); STAGE_A(0, 1, 0); STAGE_A(0, 2, 0); STAGE_A(0, 3, 0);

  int kst = 64;
  const int npair = (nt >> 1) - 1;
  for (int tt = 0; tt < npair; ++tt) {
    TILE(0, kst, 1, 3, 4, 5, 6); kst += 64;
    TILE(1, kst, 1, 3, 4, 5, 6); kst += 64;
  }
  TILE(0, kst, 1, 3, 4, 5, 6);   // tile nt-2 stages tile nt-1
  TILE(1, 0, 0, 3, 2, 1, 0);     // tile nt-1, no prefetch, drain

#undef TILE
#undef DO_MFMA
#undef LDA
#undef STAGE_A
#undef STAGE_B

  // ---- epilogue: per-wave-private LDS re-swizzle, coalesced 16B stores.
  // C/D layout: col = lane&15, row = (lane>>4)*4 + reg   [m89-verified]
  __syncthreads();
  float* scratch = (float*)smem + wv * 1088;  // 16 rows x 68 fp32
  const int qd = ln >> 4;
#pragma unroll
  for (int i = 0; i < 8; ++i) {
#pragma unroll
    for (int j = 0; j < 4; ++j)
#pragma unroll
      for (int r = 0; r < 4; ++r)
        scratch[(qd * 4 + r) * 68 + j * 16 + lr] = acc[i][j][r];
    asm volatile("s_waitcnt lgkmcnt(0)" ::: "memory");
#pragma unroll
    for (int s = 0; s < 4; ++s) {
      int rr = qd + 4 * s;
      f32x4 vv = *(f32x4*)&scratch[rr * 68 + lr * 4];
      int row = m0 + wm + i * 16 + rr;
      int col = n0 + wn + lr * 4;
      size_t idx = (size_t)row * N + col;
      vv += *(const f32x4*)&bias[col];
      if (EPI == 1) vv += *(const f32x4*)&res[idx];
      if constexpr (sizeof(CT) == 4) {
        *(f32x4*)&C[idx] = vv;
      } else {
        bf16x4 o;
#pragma unroll
        for (int t2 = 0; t2 < 4; ++t2) o[t2] = (__bf16)vv[t2];
        *(bf16x4*)&C[idx] = o;
      }
    }
    asm volatile("s_waitcnt lgkmcnt(0)" ::: "memory");
  }
}

// gemm_dual: blocks [0,n0) do GEMM0 (q-proj), [n0,grid) do GEMM1 (kv-proj)
__global__ __launch_bounds__(512, 2)
void gemm_dual(const __bf16* __restrict__ A0, const __bf16* __restrict__ B0,
               const float* __restrict__ bias0, __bf16* __restrict__ C0,
               int K0, int NT0, int n0,
               const __bf16* __restrict__ A1, const __bf16* __restrict__ B1,
               const float* __restrict__ bias1, __bf16* __restrict__ C1,
               int K1, int NT1) {
  __shared__ char smem[131072];
  int bid = blockIdx.x;
  if (bid < n0)
    gemm_body<0, __bf16>(smem, A0, B0, bias0, nullptr, C0, K0, NT0, bid, n0);
  else
    gemm_body<0, __bf16>(smem, A1, B1, bias1, nullptr, C1, K1, NT1, bid - n0,
                         (int)gridDim.x - n0);
}

// out-projection: fp32 out + residual
__global__ __launch_bounds__(512, 2)
void gemm_ep(const __bf16* __restrict__ A, const __bf16* __restrict__ BT,
             const float* __restrict__ bias, const float* __restrict__ res,
             float* __restrict__ C, int K, int NT) {
  __shared__ char smem[131072];
  gemm_body<1, float>(smem, A, BT, bias, res, C, K, NT, blockIdx.x,
                      (int)gridDim.x);
}

// ---------------------------------------------------------------------------
// attn_emb: ONE launch.
//   blocks [0,512):    attn[b,h,c,d] = sum_n softmax_n(k)[n,c] * v[n,d]
//   blocks [512,1536): ss += silu(emb) @ emb_W  (4-way K-split, atomicAdd)
// ---------------------------------------------------------------------------
__global__ __launch_bounds__(256)
void attn_emb(const __bf16* __restrict__ kv, float* __restrict__ attn,
              const float* __restrict__ emb, const float* __restrict__ W,
              float* __restrict__ ss) {
  __shared__ __bf16 sK[256 * 72];
  __shared__ float sV[64 * 64];
  __shared__ float sInv[64];
  __shared__ float se[512];
  int tid = threadIdx.x;

  if (blockIdx.x >= 512) {
    // ---- emb_gemm segment
    int bid = blockIdx.x - 512;
    int b  = bid >> 5;
    int nc = (bid >> 2) & 7;
    int kq = bid & 3;
    int k0 = kq * 512;
    for (int i = tid; i < 512; i += 256) {
      float xv = emb[(size_t)b * TE_ + k0 + i];
      se[i] = xv / (1.f + __expf(-xv));
    }
    __syncthreads();
    int n = nc * 256 + tid;
    float acc = 0.f;
    for (int kk = 0; kk < 512; kk++)
      acc += se[kk] * W[(size_t)(k0 + kk) * 2048 + n];
    atomicAdd(&ss[(size_t)b * 2048 + n], acc);
    return;
  }

  // ---- kv_attn segment
  int h = blockIdx.x & 15, b = blockIdx.x >> 4;
  const __bf16* kb = kv + (size_t)b * N_ * 2048 + h * C_;
  const __bf16* vb = kb + 1024;

  {
    const __bf16* src = kb + (size_t)tid * 2048;
#pragma unroll
    for (int j = 0; j < 8; j++)
      *(bf16x8*)&sK[tid * 72 + j * 8] = *(const bf16x8*)(src + j * 8);
  }
  __syncthreads();

  {
    int c = tid >> 2, qq = tid & 3;
    float m = -1e30f;
    for (int t = 0; t < 64; t++)
      m = fmaxf(m, (float)sK[(qq * 64 + t) * 72 + c]);
    m = fmaxf(m, __shfl_xor(m, 1));
    m = fmaxf(m, __shfl_xor(m, 2));
    float s = 0.f;
    for (int t = 0; t < 64; t++) {
      int idx = (qq * 64 + t) * 72 + c;
      float e = __expf((float)sK[idx] - m);
      sK[idx] = (__bf16)e;
      s += e;
    }
    s += __shfl_xor(s, 1);
    s += __shfl_xor(s, 2);
    if (qq == 0) sInv[c] = 1.f / s;
  }
  __syncthreads();

  int c0 = (tid & 15) * 4, d0 = (tid >> 4) * 4;
  float acc[4][4] = {};
  for (int n0 = 0; n0 < N_; n0 += 64) {
    __syncthreads();
    {
      int r = tid >> 2, s8 = (tid & 3) * 16;
      const __bf16* vr = vb + (size_t)(n0 + r) * 2048 + s8;
      bf16x8 a0 = *(const bf16x8*)vr;
      bf16x8 a1 = *(const bf16x8*)(vr + 8);
#pragma unroll
      for (int j = 0; j < 8; j++) {
        sV[r * 64 + s8 + j] = (float)a0[j];
        sV[r * 64 + s8 + 8 + j] = (float)a1[j];
      }
    }
    __syncthreads();
    for (int n = 0; n < 64; n++) {
      bf16x4 kk = *(const bf16x4*)&sK[(n0 + n) * 72 + c0];
      f32x4 vd = *(const f32x4*)&sV[n * 64 + d0];
#pragma unroll
      for (int i = 0; i < 4; i++) {
        float kf = (float)kk[i];
#pragma unroll
        for (int j = 0; j < 4; j++) acc[i][j] += kf * vd[j];
      }
    }
  }
  float* ab = attn + (size_t)(b * H_ + h) * 4096;
#pragma unroll
  for (int i = 0; i < 4; i++) {
    float inv = sInv[c0 + i];
    f32x4 o;
#pragma unroll
    for (int j = 0; j < 4; j++) o[j] = acc[i][j] * inv;
    *(f32x4*)&ab[(c0 + i) * 64 + d0] = o;
  }
}

// ---------------------------------------------------------------------------
// y[b,t,h,:] = softmax_c(q[b,t,h,:]) @ attn[b,h]   (channel softmax fused)
// In-place safe (y aliases q): q tile fully staged to LDS before writes.
// ---------------------------------------------------------------------------
__global__ __launch_bounds__(256)
void qattn_y(const __bf16* __restrict__ q, const float* __restrict__ attn,
             __bf16* __restrict__ y) {
  int tt = blockIdx.x * 64;
  int h = blockIdx.y, b = blockIdx.z;
  __shared__ float sQ[64 * 65];  // [c][r], stride 65
  __shared__ float sA[64 * 64];  // [c][d]
  int tid = threadIdx.x;
  const __bf16* qb = q + ((size_t)b * T_ + tt) * D_ + h * C_;
#pragma unroll
  for (int it = 0; it < 2; it++) {
    int r = (tid >> 3) + it * 32;
    int cc = (tid & 7) * 8;
    bf16x8 vv = *(const bf16x8*)(qb + (size_t)r * D_ + cc);
#pragma unroll
    for (int j = 0; j < 8; j++) sQ[(cc + j) * 65 + r] = (float)vv[j];
  }
  const float* ab = attn + (size_t)(b * H_ + h) * 4096;
  for (int i = tid; i < 1024; i += 256) ((f32x4*)sA)[i] = ((const f32x4*)ab)[i];
  __syncthreads();
  {
    int r = tid >> 2, sub = tid & 3;
    float m = -1e30f;
#pragma unroll
    for (int j = 0; j < 16; j++)
      m = fmaxf(m, sQ[(sub * 16 + j) * 65 + r]);
    m = fmaxf(m, __shfl_xor(m, 1));
    m = fmaxf(m, __shfl_xor(m, 2));
    float s = 0.f;
#pragma unroll
    for (int j = 0; j < 16; j++) {
      int idx = (sub * 16 + j) * 65 + r;
      float e = __expf(sQ[idx] - m);
      sQ[idx] = e;
      s += e;
    }
    s += __shfl_xor(s, 1);
    s += __shfl_xor(s, 2);
    float inv = 1.f / s;
#pragma unroll
    for (int j = 0; j < 16; j++) sQ[(sub * 16 + j) * 65 + r] *= inv;
  }
  __syncthreads();
  int r0 = (tid >> 4) * 4, d0 = (tid & 15) * 4;
  float acc[4][4] = {};
  for (int c = 0; c < 64; c++) {
    f32x4 qv = *(const f32x4*)&sQ[c * 65 + r0];
    f32x4 av = *(const f32x4*)&sA[c * 64 + d0];
#pragma unroll
    for (int i = 0; i < 4; i++)
#pragma unroll
      for (int j = 0; j < 4; j++) acc[i][j] += qv[i] * av[j];
  }
  __bf16* yb = y + ((size_t)b * T_ + tt) * D_ + h * C_;
#pragma unroll
  for (int i = 0; i < 4; i++) {
    bf16x4 o;
#pragma unroll
    for (int j = 0; j < 4; j++) o[j] = (__bf16)acc[i][j];
    *(bf16x4*)(yb + (size_t)(r0 + i) * D_ + d0) = o;
  }
}

// ---------------------------------------------------------------------------
// h_pre = silu( LN(y)*(1+scale) + shift ), vectorized; y bf16, rest fp32
// ---------------------------------------------------------------------------
__global__ __launch_bounds__(256)
void film_rows(const __bf16* __restrict__ y, const float* __restrict__ ss,
               const float* __restrict__ g, const float* __restrict__ bb,
               __bf16* __restrict__ out) {
  size_t row = blockIdx.x;
  int b = (int)(row >> 10);
  int c4 = threadIdx.x * 4;
  bf16x4 yv = *(const bf16x4*)(y + row * D_ + c4);
  float v[4];
  float s = 0.f, s2 = 0.f;
#pragma unroll
  for (int t = 0; t < 4; t++) {
    v[t] = (float)yv[t];
    s += v[t]; s2 += v[t] * v[t];
  }
#pragma unroll
  for (int off = 32; off; off >>= 1) {
    s += __shfl_down(s, off);
    s2 += __shfl_down(s2, off);
  }
  __shared__ float red[8];
  int wave = threadIdx.x >> 6, lane = threadIdx.x & 63;
  if (lane == 0) { red[wave] = s; red[4 + wave] = s2; }
  __syncthreads();
  if (threadIdx.x == 0) {
    float a = 0.f, c = 0.f;
    for (int w = 0; w < 4; w++) { a += red[w]; c += red[4 + w]; }
    red[0] = a; red[4] = c;
  }
  __syncthreads();
  float mu = red[0] / D_;
  float var = red[4] / D_ - mu * mu;
  float rstd = rsqrtf(var + 1e-5f);
  f32x4 gg = *(const f32x4*)(g + c4);
  f32x4 bbv = *(const f32x4*)(bb + c4);
  f32x4 sc = *(const f32x4*)(ss + (size_t)b * 2048 + c4);
  f32x4 sh = *(const f32x4*)(ss + (size_t)b * 2048 + 1024 + c4);
  bf16x4 o;
#pragma unroll
  for (int t = 0; t < 4; t++) {
    float ln = (v[t] - mu) * rstd * gg[t] + bbv[t];
    float hh = ln * (1.f + sc[t]) + sh[t];
    o[t] = (__bf16)(hh / (1.f + __expf(-hh)));
  }
  *(bf16x4*)(out + row * D_ + c4) = o;
}

// ---------------------------------------------------------------------------
extern "C" void kernel_launch(void* const* d_in, const int* in_sizes, int n_in,
                              void* d_out, int out_size, void* d_ws,
                              size_t ws_size, hipStream_t stream) {
  (void)in_sizes; (void)n_in;
  const float* x       = (const float*)d_in[0];
  const float* xf      = (const float*)d_in[1];
  const float* emb     = (const float*)d_in[2];
  const float* norm_g  = (const float*)d_in[3];
  const float* norm_b  = (const float*)d_in[4];
  const float* tnorm_g = (const float*)d_in[5];
  const float* tnorm_b = (const float*)d_in[6];
  const float* Wq      = (const float*)d_in[7];
  const float* bq      = (const float*)d_in[8];
  const float* Wk      = (const float*)d_in[9];
  const float* bk      = (const float*)d_in[10];
  const float* Wv      = (const float*)d_in[11];
  const float* bv      = (const float*)d_in[12];
  const float* emb_W   = (const float*)d_in[13];
  const float* emb_b   = (const float*)d_in[14];
  const float* fnorm_g = (const float*)d_in[15];
  const float* fnorm_b = (const float*)d_in[16];
  const float* out_W   = (const float*)d_in[17];
  const float* out_b   = (const float*)d_in[18];
  float* out = (float*)d_out;

  // -------- workspace layout --------
  const size_t SZ_WQT  = (size_t)D_ * D_ * 2;             // 2 MB   bf16
  const size_t SZ_WKVT = (size_t)2048 * TD_ * 2;          // 3 MB   bf16
  const size_t SZ_XN   = (size_t)B_ * T_ * D_ * 2;        // 64 MB  bf16
  const size_t SZ_XFN  = (size_t)B_ * N_ * TD_ * 2;       // 12 MB  bf16
  const size_t SZ_KV   = (size_t)B_ * N_ * 2048 * 2;      // 32 MB  bf16
  const size_t SZ_BKV  = 2048 * 4;                        // 8 KB   f32
  const size_t SZ_SS   = (size_t)B_ * 2048 * 4;           // 256 KB f32
  const size_t NEED =
      SZ_WQT * 2 + SZ_WKVT + SZ_XN + SZ_XFN + SZ_KV + SZ_BKV + SZ_SS;

  if (ws_size < NEED) {  // diagnostic: encode ws_size (MB) into the output
    fill_val<<<(out_size + 255) / 256, 256, 0, stream>>>(
        out, (float)(ws_size >> 20), out_size);
    return;
  }

  char* w = (char*)d_ws;
  __bf16* WqT  = (__bf16*)w; w += SZ_WQT;
  __bf16* WkvT = (__bf16*)w; w += SZ_WKVT;
  __bf16* WoT  = (__bf16*)w; w += SZ_WQT;
  __bf16* xn   = (__bf16*)w; w += SZ_XN;    // later reused as h_pre
  char*   xfnR = w;          w += SZ_XFN;   // xfn; attn overlays after death
  __bf16* kvbuf= (__bf16*)w; w += SZ_KV;
  float*  bkv  = (float*)w;  w += SZ_BKV;
  float*  ss   = (float*)w;  w += SZ_SS;    // own slot (init in preprocess)
  __bf16* xfn  = (__bf16*)xfnR;
  float*  attn = (float*)xfnR;              // alive after xfn dies (8 MB)
  __bf16* hpre = xn;            // xn dead after q-proj
  __bf16* qbuf = (__bf16*)out;  // q (bf16, 64MB) lives in d_out (128MB f32)
  __bf16* ybuf = qbuf;          // qattn_y works in-place

  // 1. all input-only prep in one launch: transposes, biases, LNs, ss init
  preprocess<<<44808, 256, 0, stream>>>(Wq, Wk, Wv, out_W, bk, bv,
                                        x, norm_g, norm_b, xf, tnorm_g,
                                        tnorm_b, emb_b,
                                        WqT, WkvT, WoT, bkv, xn, xfn, ss);

  // 2. q-proj + kv-proj fused into one 768-block launch
  gemm_dual<<<768, 512, 0, stream>>>(xn, WqT, bq, qbuf, D_, D_ / 256, 512,
                                     xfn, WkvT, bkv, kvbuf, TD_, 2048 / 256);

  // 3. attn = softmax_n(k)^T v  +  emb FiLM GEMM (independent, same launch)
  attn_emb<<<1536, 256, 0, stream>>>(kvbuf, attn, emb, emb_W, ss);

  // 4. y = softmax_c(q) @ attn  (q softmax fused, in-place in d_out)
  qattn_y<<<dim3(T_ / 64, H_, B_), 256, 0, stream>>>(qbuf, attn, ybuf);

  // 5. FiLM rows
  film_rows<<<B_ * T_, 256, 0, stream>>>(ybuf, ss, fnorm_g, fnorm_b, hpre);

  // 6. out = x + h_pre @ out_W + out_b   (fp32 output + residual)
  gemm_ep<<<512, 512, 0, stream>>>(hpre, WoT, out_b, x, out, D_, D_ / 256);
}